// Round 4
// baseline (740.811 us; speedup 1.0000x reference)
//
#include <hip/hip_runtime.h>

// LR_PINN_phase2_midout: fused 4-stage tiny MLP, N=262144, H=256, R=32.
// R4: two structural fixes over R2/R3 (whose counters showed 412 MB of
// scratch spill traffic — the loop-carried hb[16] array never fit in the
// 64-VGPR arch budget — plus 3.3M LDS conflict cycles from A-frag reads).
//
// Fix 1 — producer/consumer fusion, zero loop-carried arrays:
//   hb[t] (output tile t of GEMM2 block k) is consumed ONLY by K-tile t of
//   GEMM1 block k+1. So per t: hc = 2 MFMAs(pf) -> tanh -> h (2 VGPRs)
//   -> 2 MFMAs into next acc -> h dies. Live set ~45 VGPRs, k fully unrolled.
// Fix 2 — fragment-ordered LDS: weights stored as frag[k][t][sel][lane]
//   (half4 per lane), so every hot-loop ds_read_b64 is base + lane*8:
//   lane-linear, conflict-free by construction. LDS = 100 KB.
//
// MFMA chain (mfma_f32_16x16x16f16): C/D layout (col=lane&15=point,
// row=4q+reg) == next MFMA's B-frag layout (k=4q+jj) -> the whole
// phase0 -> (GEMM1 -> GEMM2 -> tanh)^3 -> dot chain is layout-closed in
// registers; only cross-lane op is the final 2-shuffle reduce.

typedef _Float16 half4_t __attribute__((ext_vector_type(4)));
typedef float    float4_t __attribute__((ext_vector_type(4)));

namespace {

struct Smem {
  // entry index e = ((k*16+t)*2+sel)*64+lane
  half4_t ctf[3 * 16 * 2 * 64];  // 48 KB: Ct[sel*16+m][16t+4q+jj] * alpha  (A-frags, GEMM1)
  half4_t rwf[3 * 16 * 2 * 64];  // 48 KB: R[16t+m][sel*16+4q+jj]           (A-frags, GEMM2)
  float w0[256], w1[256], bb[256], ew[256];  // 4 KB
};

__device__ __forceinline__ float fast_tanh(float x) {
  // tanh(x) = 1 - 2/(1 + exp2(2*log2e*x)); exact saturation at +-inf.
  float e = __builtin_amdgcn_exp2f(x * 2.885390081777927f);
  return 1.0f - 2.0f * __builtin_amdgcn_rcpf(e + 1.0f);
}

__device__ __forceinline__ half4_t tanh4_pack(float4_t v) {
  half4_t h;
  h.x = (_Float16)fast_tanh(v.x);
  h.y = (_Float16)fast_tanh(v.y);
  h.z = (_Float16)fast_tanh(v.z);
  h.w = (_Float16)fast_tanh(v.w);
  return h;
}

__global__ __launch_bounds__(1024, 4) void pinn_fused(
    const float* __restrict__ xg, const float* __restrict__ tg,
    const float* __restrict__ sw, const float* __restrict__ sb,
    const float* __restrict__ ewp, const float* __restrict__ ebp,
    const float* __restrict__ c0, const float* __restrict__ c1,
    const float* __restrict__ c2, const float* __restrict__ r0,
    const float* __restrict__ r1, const float* __restrict__ r2,
    const float* __restrict__ a0, const float* __restrict__ a1,
    const float* __restrict__ a2, float* __restrict__ out, int n)
{
  __shared__ Smem sm;
  const int tid = threadIdx.x;

  // ---- stage weights into fragment-ordered fp16 LDS (once per block) ----
  for (int e = tid; e < 3 * 16 * 2 * 64; e += 1024) {
    const int lane_ = e & 63;
    const int sel   = (e >> 6) & 1;
    const int t_    = (e >> 7) & 15;
    const int k_    = e >> 11;
    const int m_ = lane_ & 15, q_ = lane_ >> 4;
    const float* ck = (k_ == 0) ? c0 : (k_ == 1) ? c1 : c2;
    const float* rk = (k_ == 0) ? r0 : (k_ == 1) ? r1 : r2;
    const float* ak = (k_ == 0) ? a0 : (k_ == 1) ? a1 : a2;
    {  // Ct frag: A-row r = sel*16+m, cols j = 16t+4q+jj ; fold diag(alpha)
      const int r = sel * 16 + m_;
      const float av = ak[r];
      const int j0 = 16 * t_ + 4 * q_;
      half4_t v;
      v.x = (_Float16)(ck[(j0 + 0) * 32 + r] * av);
      v.y = (_Float16)(ck[(j0 + 1) * 32 + r] * av);
      v.z = (_Float16)(ck[(j0 + 2) * 32 + r] * av);
      v.w = (_Float16)(ck[(j0 + 3) * 32 + r] * av);
      sm.ctf[e] = v;
    }
    {  // R frag: A-row j = 16t+m, cols r = sel*16+4q+jj
      const int j = 16 * t_ + m_;
      const int rr = sel * 16 + 4 * q_;
      half4_t v;
      v.x = (_Float16)rk[j * 32 + rr + 0];
      v.y = (_Float16)rk[j * 32 + rr + 1];
      v.z = (_Float16)rk[j * 32 + rr + 2];
      v.w = (_Float16)rk[j * 32 + rr + 3];
      sm.rwf[e] = v;
    }
  }
  if (tid < 256) {
    sm.w0[tid] = sw[2 * tid];
    sm.w1[tid] = sw[2 * tid + 1];
    sm.bb[tid] = sb[tid];
    sm.ew[tid] = ewp[tid];
  }
  __syncthreads();  // the only barrier

  const int wave = tid >> 6;
  const int lane = tid & 63;
  const int m = lane & 15;   // point index (MFMA col / A-row / B-col)
  const int q = lane >> 4;   // quad
  const int wo = 4 * q;      // j = 16t + 4q + jj
  const float ebv = ebp[0];
  const int tiles = n >> 4;

  for (int g = blockIdx.x * 16 + wave; g < tiles; g += 4096) {
    const int n0 = g * 16;
    const float xm = xg[n0 + m];
    const float tm = tg[n0 + m];

    // ---- phase0 fused with GEMM1(k=0): per tile t, h is transient ----
    float4_t acc0 = {0.f, 0.f, 0.f, 0.f};
    float4_t acc1 = {0.f, 0.f, 0.f, 0.f};
#pragma unroll
    for (int t = 0; t < 16; ++t) {
      const int cb = t * 16 + wo;
      const float4_t w0v = *(const float4_t*)&sm.w0[cb];  // broadcast reads
      const float4_t w1v = *(const float4_t*)&sm.w1[cb];
      const float4_t bv  = *(const float4_t*)&sm.bb[cb];
      float4_t z;
      z.x = fmaf(xm, w0v.x, fmaf(tm, w1v.x, bv.x));
      z.y = fmaf(xm, w0v.y, fmaf(tm, w1v.y, bv.y));
      z.z = fmaf(xm, w0v.z, fmaf(tm, w1v.z, bv.z));
      z.w = fmaf(xm, w0v.w, fmaf(tm, w1v.w, bv.w));
      const half4_t h = tanh4_pack(z);
      const int cbase = (t * 2) * 64 + lane;  // k=0 frags
      acc0 = __builtin_amdgcn_mfma_f32_16x16x16f16(sm.ctf[cbase], h, acc0, 0, 0, 0);
      acc1 = __builtin_amdgcn_mfma_f32_16x16x16f16(sm.ctf[cbase + 64], h, acc1, 0, 0, 0);
    }

    float ssum = 0.0f;
#pragma unroll
    for (int k = 0; k < 3; ++k) {
      // acc (= P^T, r = 4q+reg) is already the next B-frag: just pack fp16.
      const half4_t pfA = {(_Float16)acc0.x, (_Float16)acc0.y, (_Float16)acc0.z, (_Float16)acc0.w};
      const half4_t pfB = {(_Float16)acc1.x, (_Float16)acc1.y, (_Float16)acc1.z, (_Float16)acc1.w};

      if (k < 2) {
        // GEMM2(k) fused with GEMM1(k+1): h per tile is transient.
        float4_t na = {0.f, 0.f, 0.f, 0.f};
        float4_t nb = {0.f, 0.f, 0.f, 0.f};
#pragma unroll
        for (int t = 0; t < 16; ++t) {
          const int rbase = ((k * 16 + t) * 2) * 64 + lane;
          float4_t hc = {0.f, 0.f, 0.f, 0.f};
          hc = __builtin_amdgcn_mfma_f32_16x16x16f16(sm.rwf[rbase], pfA, hc, 0, 0, 0);
          hc = __builtin_amdgcn_mfma_f32_16x16x16f16(sm.rwf[rbase + 64], pfB, hc, 0, 0, 0);
          const half4_t h = tanh4_pack(hc);  // D layout == next B-frag layout
          const int cbase = (((k + 1) * 16 + t) * 2) * 64 + lane;
          na = __builtin_amdgcn_mfma_f32_16x16x16f16(sm.ctf[cbase], h, na, 0, 0, 0);
          nb = __builtin_amdgcn_mfma_f32_16x16x16f16(sm.ctf[cbase + 64], h, nb, 0, 0, 0);
        }
        acc0 = na;
        acc1 = nb;
      } else {
        // last block: GEMM2(2) fused with the end_w dot (fp32 epilogue)
#pragma unroll
        for (int t = 0; t < 16; ++t) {
          const int rbase = ((k * 16 + t) * 2) * 64 + lane;
          float4_t hc = {0.f, 0.f, 0.f, 0.f};
          hc = __builtin_amdgcn_mfma_f32_16x16x16f16(sm.rwf[rbase], pfA, hc, 0, 0, 0);
          hc = __builtin_amdgcn_mfma_f32_16x16x16f16(sm.rwf[rbase + 64], pfB, hc, 0, 0, 0);
          const float4_t ev = *(const float4_t*)&sm.ew[t * 16 + wo];
          ssum += fast_tanh(hc.x) * ev.x + fast_tanh(hc.y) * ev.y
                + fast_tanh(hc.z) * ev.z + fast_tanh(hc.w) * ev.w;
        }
      }
    }
    // each lane holds the partial dot over its j-subset; reduce over the 4 quads
    ssum += __shfl_xor(ssum, 16);
    ssum += __shfl_xor(ssum, 32);
    if (lane < 16) out[n0 + m] = ssum + ebv;
  }
}

}  // namespace

extern "C" void kernel_launch(void* const* d_in, const int* in_sizes, int n_in,
                              void* d_out, int out_size, void* d_ws, size_t ws_size,
                              hipStream_t stream) {
  const float* xg  = (const float*)d_in[0];
  const float* tg  = (const float*)d_in[1];
  const float* sw  = (const float*)d_in[2];
  const float* sb  = (const float*)d_in[3];
  const float* ewp = (const float*)d_in[4];
  const float* ebp = (const float*)d_in[5];
  const float* c0  = (const float*)d_in[6];
  const float* c1  = (const float*)d_in[7];
  const float* c2  = (const float*)d_in[8];
  const float* r0  = (const float*)d_in[9];
  const float* r1  = (const float*)d_in[10];
  const float* r2  = (const float*)d_in[11];
  const float* a0  = (const float*)d_in[12];
  const float* a1  = (const float*)d_in[13];
  const float* a2  = (const float*)d_in[14];
  float* outp = (float*)d_out;

  const int n = in_sizes[0];  // 262144

  pinn_fused<<<256, 1024, 0, stream>>>(xg, tg, sw, sb, ewp, ebp,
                                       c0, c1, c2, r0, r1, r2, a0, a1, a2,
                                       outp, n);
}

// Round 5
// 162.142 us; speedup vs baseline: 4.5689x; 4.5689x over previous
//
#include <hip/hip_runtime.h>

// LR_PINN_phase2_midout: fused 4-stage tiny MLP, N=262144, H=256, R=32.
// R5 = R4's dataflow + strict #pragma unroll 1 everywhere.
// R4 post-mortem: full unroll of the k/t loops let the scheduler hoist ~200
// ds_reads -> live set exploded under the 64-VGPR arch budget -> 1.8 GB of
// scratch spill traffic (kernel ran at scratch BW: 673 us). The dataflow
// itself (transient h, no loop-carried arrays) and the fragment-ordered LDS
// (bank conflicts 3.3M -> 0) are both correct and kept.
//
// R5 principle: live set must fit 64 VGPRs BY CONSTRUCTION. Every loop is
// unroll-1; each body is ~25 instr with ~30 live regs. Latency per iter is
// hidden by 4 waves/SIMD (16-wave block, LDS 100 KB -> 1 block/CU).
//
// MFMA chain (mfma_f32_16x16x16f16): C/D layout (col=lane&15=point,
// row=4q+reg) == next MFMA's B-frag layout (k=4q+jj) -> phase0 ->
// (GEMM1 -> GEMM2 -> tanh)^3 -> dot is layout-closed in registers; only
// cross-lane op is the final 2-shuffle reduce.

typedef _Float16 half4_t __attribute__((ext_vector_type(4)));
typedef float    float4_t __attribute__((ext_vector_type(4)));

namespace {

struct Smem {
  // entry index e = ((k*16+t)*2+sel)*64+lane ; one half4 (8 B) per lane.
  // Hot-loop reads are base + lane*8 + imm -> lane-linear, conflict-free.
  half4_t ctf[3 * 16 * 2 * 64];  // 48 KB: Ct[sel*16+m][16t+4q+jj] * alpha  (A-frags, GEMM1)
  half4_t rwf[3 * 16 * 2 * 64];  // 48 KB: R[16t+m][sel*16+4q+jj]           (A-frags, GEMM2)
  float w0[256], w1[256], bb[256], ew[256];  // 4 KB
};

__device__ __forceinline__ float fast_tanh(float x) {
  // tanh(x) = 1 - 2/(1 + exp2(2*log2e*x)); exact saturation at +-inf.
  float e = __builtin_amdgcn_exp2f(x * 2.885390081777927f);
  return 1.0f - 2.0f * __builtin_amdgcn_rcpf(e + 1.0f);
}

__device__ __forceinline__ half4_t tanh4_pack(float4_t v) {
  half4_t h;
  h.x = (_Float16)fast_tanh(v.x);
  h.y = (_Float16)fast_tanh(v.y);
  h.z = (_Float16)fast_tanh(v.z);
  h.w = (_Float16)fast_tanh(v.w);
  return h;
}

__global__ __launch_bounds__(1024) void pinn_fused(
    const float* __restrict__ xg, const float* __restrict__ tg,
    const float* __restrict__ sw, const float* __restrict__ sb,
    const float* __restrict__ ewp, const float* __restrict__ ebp,
    const float* __restrict__ c0, const float* __restrict__ c1,
    const float* __restrict__ c2, const float* __restrict__ r0,
    const float* __restrict__ r1, const float* __restrict__ r2,
    const float* __restrict__ a0, const float* __restrict__ a1,
    const float* __restrict__ a2, float* __restrict__ out, int n)
{
  __shared__ Smem sm;
  const int tid = threadIdx.x;

  // ---- stage weights into fragment-ordered fp16 LDS (once per block) ----
  for (int e = tid; e < 3 * 16 * 2 * 64; e += 1024) {
    const int lane_ = e & 63;
    const int sel   = (e >> 6) & 1;
    const int t_    = (e >> 7) & 15;
    const int k_    = e >> 11;
    const int m_ = lane_ & 15, q_ = lane_ >> 4;
    const float* ck = (k_ == 0) ? c0 : (k_ == 1) ? c1 : c2;
    const float* rk = (k_ == 0) ? r0 : (k_ == 1) ? r1 : r2;
    const float* ak = (k_ == 0) ? a0 : (k_ == 1) ? a1 : a2;
    {  // Ct frag: A-row r = sel*16+m, cols j = 16t+4q+jj ; fold diag(alpha)
      const int r = sel * 16 + m_;
      const float av = ak[r];
      const int j0 = 16 * t_ + 4 * q_;
      half4_t v;
      v.x = (_Float16)(ck[(j0 + 0) * 32 + r] * av);
      v.y = (_Float16)(ck[(j0 + 1) * 32 + r] * av);
      v.z = (_Float16)(ck[(j0 + 2) * 32 + r] * av);
      v.w = (_Float16)(ck[(j0 + 3) * 32 + r] * av);
      sm.ctf[e] = v;
    }
    {  // R frag: A-row j = 16t+m, cols r = sel*16+4q+jj
      const int j = 16 * t_ + m_;
      const int rr = sel * 16 + 4 * q_;
      half4_t v;
      v.x = (_Float16)rk[j * 32 + rr + 0];
      v.y = (_Float16)rk[j * 32 + rr + 1];
      v.z = (_Float16)rk[j * 32 + rr + 2];
      v.w = (_Float16)rk[j * 32 + rr + 3];
      sm.rwf[e] = v;
    }
  }
  if (tid < 256) {
    sm.w0[tid] = sw[2 * tid];
    sm.w1[tid] = sw[2 * tid + 1];
    sm.bb[tid] = sb[tid];
    sm.ew[tid] = ewp[tid];
  }
  __syncthreads();  // the only barrier

  const int wave = tid >> 6;
  const int lane = tid & 63;
  const int m = lane & 15;   // point index (MFMA col / A-row / B-col)
  const int q = lane >> 4;   // quad
  const int wo = 4 * q;      // j = 16t + 4q + jj
  const float ebv = ebp[0];
  const int tiles = n >> 4;

#pragma unroll 1
  for (int g = blockIdx.x * 16 + wave; g < tiles; g += 4096) {
    const int n0 = g * 16;
    const float xm = xg[n0 + m];
    const float tm = tg[n0 + m];

    // ---- phase0 fused with GEMM1(k=0): per tile t, h is transient ----
    float4_t acc0 = {0.f, 0.f, 0.f, 0.f};
    float4_t acc1 = {0.f, 0.f, 0.f, 0.f};
#pragma unroll 1
    for (int t = 0; t < 16; ++t) {
      const int cb = t * 16 + wo;
      const float4_t w0v = *(const float4_t*)&sm.w0[cb];  // broadcast reads
      const float4_t w1v = *(const float4_t*)&sm.w1[cb];
      const float4_t bv  = *(const float4_t*)&sm.bb[cb];
      float4_t z;
      z.x = fmaf(xm, w0v.x, fmaf(tm, w1v.x, bv.x));
      z.y = fmaf(xm, w0v.y, fmaf(tm, w1v.y, bv.y));
      z.z = fmaf(xm, w0v.z, fmaf(tm, w1v.z, bv.z));
      z.w = fmaf(xm, w0v.w, fmaf(tm, w1v.w, bv.w));
      const half4_t h = tanh4_pack(z);
      const half4_t* cp = &sm.ctf[t * 128 + lane];  // k=0 frags
      acc0 = __builtin_amdgcn_mfma_f32_16x16x16f16(cp[0], h, acc0, 0, 0, 0);
      acc1 = __builtin_amdgcn_mfma_f32_16x16x16f16(cp[64], h, acc1, 0, 0, 0);
    }

    float ssum = 0.0f;
#pragma unroll 1
    for (int k = 0; k < 3; ++k) {
      // acc (= P^T, r = 4q+reg) is already the next B-frag: just pack fp16.
      const half4_t pfA = {(_Float16)acc0.x, (_Float16)acc0.y, (_Float16)acc0.z, (_Float16)acc0.w};
      const half4_t pfB = {(_Float16)acc1.x, (_Float16)acc1.y, (_Float16)acc1.z, (_Float16)acc1.w};

      if (k < 2) {
        // GEMM2(k) fused with GEMM1(k+1): h per tile is transient.
        float4_t na = {0.f, 0.f, 0.f, 0.f};
        float4_t nb = {0.f, 0.f, 0.f, 0.f};
        const half4_t* rp = &sm.rwf[k * 2048 + lane];
        const half4_t* cp = &sm.ctf[(k + 1) * 2048 + lane];
#pragma unroll 1
        for (int t = 0; t < 16; ++t) {
          float4_t hc = {0.f, 0.f, 0.f, 0.f};
          hc = __builtin_amdgcn_mfma_f32_16x16x16f16(rp[0], pfA, hc, 0, 0, 0);
          hc = __builtin_amdgcn_mfma_f32_16x16x16f16(rp[64], pfB, hc, 0, 0, 0);
          const half4_t h = tanh4_pack(hc);  // D layout == next B-frag layout
          na = __builtin_amdgcn_mfma_f32_16x16x16f16(cp[0], h, na, 0, 0, 0);
          nb = __builtin_amdgcn_mfma_f32_16x16x16f16(cp[64], h, nb, 0, 0, 0);
          rp += 128;
          cp += 128;
        }
        acc0 = na;
        acc1 = nb;
      } else {
        // last block: GEMM2(2) fused with the end_w dot (fp32 epilogue)
        const half4_t* rp = &sm.rwf[2 * 2048 + lane];
#pragma unroll 1
        for (int t = 0; t < 16; ++t) {
          float4_t hc = {0.f, 0.f, 0.f, 0.f};
          hc = __builtin_amdgcn_mfma_f32_16x16x16f16(rp[0], pfA, hc, 0, 0, 0);
          hc = __builtin_amdgcn_mfma_f32_16x16x16f16(rp[64], pfB, hc, 0, 0, 0);
          const float4_t ev = *(const float4_t*)&sm.ew[t * 16 + wo];
          ssum += fast_tanh(hc.x) * ev.x + fast_tanh(hc.y) * ev.y
                + fast_tanh(hc.z) * ev.z + fast_tanh(hc.w) * ev.w;
          rp += 128;
        }
      }
    }
    // each lane holds the partial dot over its j-subset; reduce over the 4 quads
    ssum += __shfl_xor(ssum, 16);
    ssum += __shfl_xor(ssum, 32);
    if (lane < 16) out[n0 + m] = ssum + ebv;
  }
}

}  // namespace

extern "C" void kernel_launch(void* const* d_in, const int* in_sizes, int n_in,
                              void* d_out, int out_size, void* d_ws, size_t ws_size,
                              hipStream_t stream) {
  const float* xg  = (const float*)d_in[0];
  const float* tg  = (const float*)d_in[1];
  const float* sw  = (const float*)d_in[2];
  const float* sb  = (const float*)d_in[3];
  const float* ewp = (const float*)d_in[4];
  const float* ebp = (const float*)d_in[5];
  const float* c0  = (const float*)d_in[6];
  const float* c1  = (const float*)d_in[7];
  const float* c2  = (const float*)d_in[8];
  const float* r0  = (const float*)d_in[9];
  const float* r1  = (const float*)d_in[10];
  const float* r2  = (const float*)d_in[11];
  const float* a0  = (const float*)d_in[12];
  const float* a1  = (const float*)d_in[13];
  const float* a2  = (const float*)d_in[14];
  float* outp = (float*)d_out;

  const int n = in_sizes[0];  // 262144

  pinn_fused<<<256, 1024, 0, stream>>>(xg, tg, sw, sb, ewp, ebp,
                                       c0, c1, c2, r0, r1, r2, a0, a1, a2,
                                       outp, n);
}

// Round 6
// 153.804 us; speedup vs baseline: 4.8166x; 1.0542x over previous
//
#include <hip/hip_runtime.h>

// LR_PINN_phase2_midout: fused 4-stage tiny MLP, N=262144, H=256, R=32.
// R6 = R5 + dual point-tile streams per wave.
// R5 counters: spill gone (WRITE 1 MB), conflicts 0, VALUBusy 72%, wall
// ~14.2k cyc/wave-iter vs ~7.1k issue cyc -> ~28% dependency stall (one
// chain, 4 waves/SIMD, LDS-capped occupancy). Fix: each wave computes TWO
// independent 16-point tiles, sharing every LDS fragment read and every
// loop body. Two independent MFMA->tanh chains per unroll-1 body give the
// scheduler in-body ILP with nothing to hoist across iterations.
// VGPR budget pinned honestly via amdgpu_waves_per_eu(4,4): LDS (100 KB)
// already forces 1 block/CU = 4 waves/SIMD, so a 128-reg budget is free.
//
// MFMA chain (mfma_f32_16x16x16f16): C/D layout (col=lane&15=point,
// row=4q+reg) == next MFMA's B-frag layout (k=4q+jj) -> phase0 ->
// (GEMM1 -> GEMM2 -> tanh)^3 -> dot is layout-closed in registers; only
// cross-lane op is the final 2-shuffle reduce. Fragment-ordered LDS:
// every hot read is base + lane*8 -> conflict-free by construction.

typedef _Float16 half4_t __attribute__((ext_vector_type(4)));
typedef float    float4_t __attribute__((ext_vector_type(4)));

namespace {

struct Smem {
  // entry index e = ((k*16+t)*2+sel)*64+lane ; one half4 (8 B) per lane.
  half4_t ctf[3 * 16 * 2 * 64];  // 48 KB: Ct[sel*16+m][16t+4q+jj] * alpha  (A-frags, GEMM1)
  half4_t rwf[3 * 16 * 2 * 64];  // 48 KB: R[16t+m][sel*16+4q+jj]           (A-frags, GEMM2)
  float w0[256], w1[256], bb[256], ew[256];  // 4 KB
};

__device__ __forceinline__ float fast_tanh(float x) {
  // tanh(x) = 1 - 2/(1 + exp2(2*log2e*x)); exact saturation at +-inf.
  float e = __builtin_amdgcn_exp2f(x * 2.885390081777927f);
  return 1.0f - 2.0f * __builtin_amdgcn_rcpf(e + 1.0f);
}

__device__ __forceinline__ half4_t tanh4_pack(float4_t v) {
  half4_t h;
  h.x = (_Float16)fast_tanh(v.x);
  h.y = (_Float16)fast_tanh(v.y);
  h.z = (_Float16)fast_tanh(v.z);
  h.w = (_Float16)fast_tanh(v.w);
  return h;
}

__device__ __forceinline__ half4_t pack16(float4_t v) {
  half4_t h;
  h.x = (_Float16)v.x; h.y = (_Float16)v.y; h.z = (_Float16)v.z; h.w = (_Float16)v.w;
  return h;
}

__global__ __launch_bounds__(1024)
__attribute__((amdgpu_waves_per_eu(4, 4)))
void pinn_fused(
    const float* __restrict__ xg, const float* __restrict__ tg,
    const float* __restrict__ sw, const float* __restrict__ sb,
    const float* __restrict__ ewp, const float* __restrict__ ebp,
    const float* __restrict__ c0, const float* __restrict__ c1,
    const float* __restrict__ c2, const float* __restrict__ r0,
    const float* __restrict__ r1, const float* __restrict__ r2,
    const float* __restrict__ a0, const float* __restrict__ a1,
    const float* __restrict__ a2, float* __restrict__ out, int n)
{
  __shared__ Smem sm;
  const int tid = threadIdx.x;

  // ---- stage weights into fragment-ordered fp16 LDS (once per block) ----
  for (int e = tid; e < 3 * 16 * 2 * 64; e += 1024) {
    const int lane_ = e & 63;
    const int sel   = (e >> 6) & 1;
    const int t_    = (e >> 7) & 15;
    const int k_    = e >> 11;
    const int m_ = lane_ & 15, q_ = lane_ >> 4;
    const float* ck = (k_ == 0) ? c0 : (k_ == 1) ? c1 : c2;
    const float* rk = (k_ == 0) ? r0 : (k_ == 1) ? r1 : r2;
    const float* ak = (k_ == 0) ? a0 : (k_ == 1) ? a1 : a2;
    {  // Ct frag: A-row r = sel*16+m, cols j = 16t+4q+jj ; fold diag(alpha)
      const int r = sel * 16 + m_;
      const float av = ak[r];
      const int j0 = 16 * t_ + 4 * q_;
      half4_t v;
      v.x = (_Float16)(ck[(j0 + 0) * 32 + r] * av);
      v.y = (_Float16)(ck[(j0 + 1) * 32 + r] * av);
      v.z = (_Float16)(ck[(j0 + 2) * 32 + r] * av);
      v.w = (_Float16)(ck[(j0 + 3) * 32 + r] * av);
      sm.ctf[e] = v;
    }
    {  // R frag: A-row j = 16t+m, cols r = sel*16+4q+jj
      const int j = 16 * t_ + m_;
      const int rr = sel * 16 + 4 * q_;
      half4_t v;
      v.x = (_Float16)rk[j * 32 + rr + 0];
      v.y = (_Float16)rk[j * 32 + rr + 1];
      v.z = (_Float16)rk[j * 32 + rr + 2];
      v.w = (_Float16)rk[j * 32 + rr + 3];
      sm.rwf[e] = v;
    }
  }
  if (tid < 256) {
    sm.w0[tid] = sw[2 * tid];
    sm.w1[tid] = sw[2 * tid + 1];
    sm.bb[tid] = sb[tid];
    sm.ew[tid] = ewp[tid];
  }
  __syncthreads();  // the only barrier

  const int wave = tid >> 6;
  const int lane = tid & 63;
  const int m = lane & 15;   // point index (MFMA col / A-row / B-col)
  const int q = lane >> 4;   // quad
  const int wo = 4 * q;      // j = 16t + 4q + jj
  const float ebv = ebp[0];
  const int tiles = n >> 4;

#pragma unroll 1
  for (int g = blockIdx.x * 32 + wave * 2; g < tiles; g += 8192) {
    const int n0 = g * 16;
    const int n1 = n0 + 16;
    const float xm0 = xg[n0 + m], tm0 = tg[n0 + m];
    const float xm1 = xg[n1 + m], tm1 = tg[n1 + m];

    // ---- phase0 fused with GEMM1(k=0); two independent streams ----
    float4_t a00 = {0.f, 0.f, 0.f, 0.f}, a01 = {0.f, 0.f, 0.f, 0.f};
    float4_t a10 = {0.f, 0.f, 0.f, 0.f}, a11 = {0.f, 0.f, 0.f, 0.f};
#pragma unroll 1
    for (int t = 0; t < 16; ++t) {
      const int cb = t * 16 + wo;
      const float4_t w0v = *(const float4_t*)&sm.w0[cb];  // shared broadcast reads
      const float4_t w1v = *(const float4_t*)&sm.w1[cb];
      const float4_t bv  = *(const float4_t*)&sm.bb[cb];
      float4_t z0, z1;
      z0.x = fmaf(xm0, w0v.x, fmaf(tm0, w1v.x, bv.x));
      z0.y = fmaf(xm0, w0v.y, fmaf(tm0, w1v.y, bv.y));
      z0.z = fmaf(xm0, w0v.z, fmaf(tm0, w1v.z, bv.z));
      z0.w = fmaf(xm0, w0v.w, fmaf(tm0, w1v.w, bv.w));
      z1.x = fmaf(xm1, w0v.x, fmaf(tm1, w1v.x, bv.x));
      z1.y = fmaf(xm1, w0v.y, fmaf(tm1, w1v.y, bv.y));
      z1.z = fmaf(xm1, w0v.z, fmaf(tm1, w1v.z, bv.z));
      z1.w = fmaf(xm1, w0v.w, fmaf(tm1, w1v.w, bv.w));
      const half4_t h0 = tanh4_pack(z0);
      const half4_t h1 = tanh4_pack(z1);
      const half4_t cA = sm.ctf[t * 128 + lane];        // shared A-frags
      const half4_t cB = sm.ctf[t * 128 + 64 + lane];
      a00 = __builtin_amdgcn_mfma_f32_16x16x16f16(cA, h0, a00, 0, 0, 0);
      a01 = __builtin_amdgcn_mfma_f32_16x16x16f16(cB, h0, a01, 0, 0, 0);
      a10 = __builtin_amdgcn_mfma_f32_16x16x16f16(cA, h1, a10, 0, 0, 0);
      a11 = __builtin_amdgcn_mfma_f32_16x16x16f16(cB, h1, a11, 0, 0, 0);
    }

    float ssum0 = 0.0f, ssum1 = 0.0f;
#pragma unroll 1
    for (int k = 0; k < 3; ++k) {
      // acc (= P^T, r = 4q+reg) is already the next B-frag: just pack fp16.
      const half4_t pA0 = pack16(a00), pB0 = pack16(a01);
      const half4_t pA1 = pack16(a10), pB1 = pack16(a11);

      if (k < 2) {
        // GEMM2(k) fused with GEMM1(k+1); h per tile is transient, per stream.
        float4_t n00 = {0.f, 0.f, 0.f, 0.f}, n01 = {0.f, 0.f, 0.f, 0.f};
        float4_t n10 = {0.f, 0.f, 0.f, 0.f}, n11 = {0.f, 0.f, 0.f, 0.f};
        const half4_t* rp = &sm.rwf[k * 2048 + lane];
        const half4_t* cp = &sm.ctf[(k + 1) * 2048 + lane];
#pragma unroll 1
        for (int t = 0; t < 16; ++t) {
          const half4_t rA = rp[0], rB = rp[64];   // shared A-frags
          const half4_t cA = cp[0], cB = cp[64];
          float4_t hc0 = {0.f, 0.f, 0.f, 0.f};
          hc0 = __builtin_amdgcn_mfma_f32_16x16x16f16(rA, pA0, hc0, 0, 0, 0);
          hc0 = __builtin_amdgcn_mfma_f32_16x16x16f16(rB, pB0, hc0, 0, 0, 0);
          float4_t hc1 = {0.f, 0.f, 0.f, 0.f};
          hc1 = __builtin_amdgcn_mfma_f32_16x16x16f16(rA, pA1, hc1, 0, 0, 0);
          hc1 = __builtin_amdgcn_mfma_f32_16x16x16f16(rB, pB1, hc1, 0, 0, 0);
          const half4_t h0 = tanh4_pack(hc0);  // D layout == next B-frag layout
          const half4_t h1 = tanh4_pack(hc1);
          n00 = __builtin_amdgcn_mfma_f32_16x16x16f16(cA, h0, n00, 0, 0, 0);
          n01 = __builtin_amdgcn_mfma_f32_16x16x16f16(cB, h0, n01, 0, 0, 0);
          n10 = __builtin_amdgcn_mfma_f32_16x16x16f16(cA, h1, n10, 0, 0, 0);
          n11 = __builtin_amdgcn_mfma_f32_16x16x16f16(cB, h1, n11, 0, 0, 0);
          rp += 128;
          cp += 128;
        }
        a00 = n00; a01 = n01; a10 = n10; a11 = n11;
      } else {
        // last block: GEMM2(2) fused with the end_w dot (fp32 epilogue)
        const half4_t* rp = &sm.rwf[2 * 2048 + lane];
#pragma unroll 1
        for (int t = 0; t < 16; ++t) {
          const half4_t rA = rp[0], rB = rp[64];
          float4_t hc0 = {0.f, 0.f, 0.f, 0.f};
          hc0 = __builtin_amdgcn_mfma_f32_16x16x16f16(rA, pA0, hc0, 0, 0, 0);
          hc0 = __builtin_amdgcn_mfma_f32_16x16x16f16(rB, pB0, hc0, 0, 0, 0);
          float4_t hc1 = {0.f, 0.f, 0.f, 0.f};
          hc1 = __builtin_amdgcn_mfma_f32_16x16x16f16(rA, pA1, hc1, 0, 0, 0);
          hc1 = __builtin_amdgcn_mfma_f32_16x16x16f16(rB, pB1, hc1, 0, 0, 0);
          const float4_t ev = *(const float4_t*)&sm.ew[t * 16 + wo];
          ssum0 += fast_tanh(hc0.x) * ev.x + fast_tanh(hc0.y) * ev.y
                 + fast_tanh(hc0.z) * ev.z + fast_tanh(hc0.w) * ev.w;
          ssum1 += fast_tanh(hc1.x) * ev.x + fast_tanh(hc1.y) * ev.y
                 + fast_tanh(hc1.z) * ev.z + fast_tanh(hc1.w) * ev.w;
          rp += 128;
        }
      }
    }
    // reduce each stream's partial dot over the 4 quads
    ssum0 += __shfl_xor(ssum0, 16);
    ssum0 += __shfl_xor(ssum0, 32);
    ssum1 += __shfl_xor(ssum1, 16);
    ssum1 += __shfl_xor(ssum1, 32);
    if (lane < 16) {
      out[n0 + m] = ssum0 + ebv;
      out[n1 + m] = ssum1 + ebv;
    }
  }
}

}  // namespace

extern "C" void kernel_launch(void* const* d_in, const int* in_sizes, int n_in,
                              void* d_out, int out_size, void* d_ws, size_t ws_size,
                              hipStream_t stream) {
  const float* xg  = (const float*)d_in[0];
  const float* tg  = (const float*)d_in[1];
  const float* sw  = (const float*)d_in[2];
  const float* sb  = (const float*)d_in[3];
  const float* ewp = (const float*)d_in[4];
  const float* ebp = (const float*)d_in[5];
  const float* c0  = (const float*)d_in[6];
  const float* c1  = (const float*)d_in[7];
  const float* c2  = (const float*)d_in[8];
  const float* r0  = (const float*)d_in[9];
  const float* r1  = (const float*)d_in[10];
  const float* r2  = (const float*)d_in[11];
  const float* a0  = (const float*)d_in[12];
  const float* a1  = (const float*)d_in[13];
  const float* a2  = (const float*)d_in[14];
  float* outp = (float*)d_out;

  const int n = in_sizes[0];  // 262144

  pinn_fused<<<256, 1024, 0, stream>>>(xg, tg, sw, sb, ewp, ebp,
                                       c0, c1, c2, r0, r1, r2, a0, a1, a2,
                                       outp, n);
}